// Round 1
// baseline (275.207 us; speedup 1.0000x reference)
//
#include <hip/hip_runtime.h>
#include <math.h>

// ---------------------------------------------------------------------------
// SuperCKAN forward:
//   conv1 (k=5, grid5, n=12)  + pool -> (256,12,12,12)
//   conv2 (k=4, grid10, n=12) + pool -> (256,144,4,4)
//   conv3 (k=3, grid10, n=24) + pool -> (256,3456)
//   fc: x @ (w2@w1)^T + (b1@w2^T + b2) -> (256,10)
// All fp32. Weights merged per layer into [k][n][1+G] tables (scaler folded).
// ---------------------------------------------------------------------------

#define B_BATCH 256

// ---- prep: merged weight tables -------------------------------------------
__global__ __launch_bounds__(256) void prep_weights(
    const float* __restrict__ bw1, const float* __restrict__ sw1, const float* __restrict__ sc1,
    const float* __restrict__ bw2, const float* __restrict__ sw2, const float* __restrict__ sc2,
    const float* __restrict__ bw3, const float* __restrict__ sw3, const float* __restrict__ sc3,
    float* __restrict__ W1m, float* __restrict__ W2m, float* __restrict__ W3m)
{
    int tid = blockIdx.x * 256 + threadIdx.x;
    if (tid < 300) {                     // layer1: n<12, k<25, G=8
        int n = tid / 25, k = tid % 25;
        float sc = sc1[n * 25 + k];
        W1m[k * 108 + n * 9] = bw1[n * 25 + k];
        for (int g = 0; g < 8; ++g)
            W1m[k * 108 + n * 9 + 1 + g] = sw1[(n * 25 + k) * 8 + g] * sc;
    } else if (tid < 492) {              // layer2: n<12, k<16, G=13
        int i = tid - 300;
        int n = i / 16, k = i % 16;
        float sc = sc2[n * 16 + k];
        W2m[k * 168 + n * 14] = bw2[n * 16 + k];
        for (int g = 0; g < 13; ++g)
            W2m[k * 168 + n * 14 + 1 + g] = sw2[(n * 16 + k) * 13 + g] * sc;
    } else if (tid < 708) {              // layer3: n<24, k<9, G=13
        int i = tid - 492;
        int n = i / 9, k = i % 9;
        float sc = sc3[n * 9 + k];
        W3m[k * 336 + n * 14] = bw3[n * 9 + k];
        for (int g = 0; g < 13; ++g)
            W3m[k * 336 + n * 14 + 1 + g] = sw3[(n * 9 + k) * 13 + g] * sc;
    }
}

// ---- prep: folded bias bf = b1 @ w2^T + b2 --------------------------------
__global__ void prep_bf(const float* __restrict__ b1, const float* __restrict__ w2,
                        const float* __restrict__ b2, float* __restrict__ bf)
{
    int lane = threadIdx.x; // 64 threads
    for (int n = 0; n < 10; ++n) {
        float s = 0.f;
        for (int j = lane; j < 256; j += 64) s = fmaf(b1[j], w2[n * 256 + j], s);
        for (int o = 32; o; o >>= 1) s += __shfl_down(s, o, 64);
        if (lane == 0) bf[n] = s + b2[n];
    }
}

// ---- prep: Wf = w2 @ w1  (10 x 3456) --------------------------------------
__global__ __launch_bounds__(256) void wf_kernel(const float* __restrict__ w1,
                                                 const float* __restrict__ w2,
                                                 float* __restrict__ Wf)
{
    int gid = blockIdx.x * 256 + threadIdx.x;
    if (gid >= 34560) return;
    int n = gid / 3456, m = gid % 3456;
    float s = 0.f;
    for (int j = 0; j < 256; ++j)
        s = fmaf(w2[n * 256 + j], w1[j * 3456 + m], s);
    Wf[n * 3456 + m] = s;
}

// ---- fused KAN conv + 2x2 maxpool -----------------------------------------
// Thread quad (4 lanes, sub = 2x2 conv position) per pooled output position.
// W layout: [K*K][N][1+G]; g0/invh describe the uniform knot grid.
template <int K, int NINT, int G, int N, int C, int HIN, int WIN, int HP, int WP>
__global__ __launch_bounds__(256) void kan_conv_pool(
    const float* __restrict__ in, const float* __restrict__ W,
    float* __restrict__ out, float g0, float invh)
{
    constexpr int NF = 1 + G;
    constexpr int POS = HP * WP;
    int tid = blockIdx.x * 256 + threadIdx.x;
    constexpr int TOT = B_BATCH * C * POS * 4;
    if (tid >= TOT) return;

    int sub = tid & 3;
    int rem = tid >> 2;
    int pos = rem % POS;
    int bc  = rem / POS;               // b*C + c
    int pi = pos / WP, pj = pos % WP;
    int p = 2 * pi + (sub >> 1);
    int q = 2 * pj + (sub & 1);

    const float* inp = in + bc * (HIN * WIN);

    float acc[N];
#pragma unroll
    for (int n = 0; n < N; ++n) acc[n] = 0.f;

    for (int dy = 0; dy < K; ++dy) {
#pragma unroll
        for (int dx = 0; dx < K; ++dx) {
            float v = inp[(p + dy) * WIN + (q + dx)];

            // features: f[0]=silu(v); f[1..G]=cubic B-spline bases (4-sparse)
            float s  = (v - g0) * invh;
            float sf = floorf(s);
            int   t  = (int)sf;
            float u  = s - sf;
            float u2 = u * u, u3 = u2 * u;
            float um = 1.0f - u;
            float c0 = um * um * um * (1.0f / 6.0f);
            float c1 = (3.0f * u3 - 6.0f * u2 + 4.0f) * (1.0f / 6.0f);
            float c2 = (-3.0f * u3 + 3.0f * u2 + 3.0f * u + 1.0f) * (1.0f / 6.0f);
            float c3 = u3 * (1.0f / 6.0f);
            bool  inr = (t >= 0) && (t < NINT);
            int   i0  = t - 3;

            float f[NF];
            f[0] = v / (1.0f + __expf(-v));
#pragma unroll
            for (int g = 0; g < G; ++g) {
                int m = g - i0;
                float fg = (m == 0) ? c0 : (m == 1) ? c1 : (m == 2) ? c2
                           : (m == 3) ? c3 : 0.0f;
                f[1 + g] = inr ? fg : 0.0f;
            }

            const float* wk = W + (dy * K + dx) * (N * NF);
#pragma unroll
            for (int n = 0; n < N; ++n)
#pragma unroll
                for (int j = 0; j < NF; ++j)
                    acc[n] = fmaf(f[j], wk[n * NF + j], acc[n]);
        }
    }

    // 2x2 maxpool across the lane quad
#pragma unroll
    for (int n = 0; n < N; ++n) {
        acc[n] = fmaxf(acc[n], __shfl_xor(acc[n], 1, 64));
        acc[n] = fmaxf(acc[n], __shfl_xor(acc[n], 2, 64));
    }

    // each of the 4 lanes writes N/4 channels
    constexpr int NPL = N / 4;
    int n0 = sub * NPL;
    float* op = out + bc * (N * POS) + pos;
#pragma unroll
    for (int i = 0; i < NPL; ++i)
        op[(n0 + i) * POS] = acc[n0 + i];
}

// ---- final GEMV: out = x3 @ Wf^T + bf  (one wave per output) --------------
__global__ __launch_bounds__(256) void fc_kernel(
    const float* __restrict__ x3, const float* __restrict__ Wf,
    const float* __restrict__ bf, float* __restrict__ out)
{
    int wid  = (blockIdx.x * 256 + threadIdx.x) >> 6;
    int lane = threadIdx.x & 63;
    if (wid >= B_BATCH * 10) return;
    int b = wid / 10, n = wid - b * 10;
    const float* xr = x3 + b * 3456;
    const float* wr = Wf + n * 3456;
    float s = 0.f;
    for (int t = lane; t < 3456; t += 64)
        s = fmaf(xr[t], wr[t], s);
    for (int o = 32; o; o >>= 1) s += __shfl_down(s, o, 64);
    if (lane == 0) out[wid] = s + bf[n];
}

// ---------------------------------------------------------------------------
extern "C" void kernel_launch(void* const* d_in, const int* in_sizes, int n_in,
                              void* d_out, int out_size, void* d_ws, size_t ws_size,
                              hipStream_t stream)
{
    (void)in_sizes; (void)n_in; (void)out_size; (void)ws_size;
    const float* x   = (const float*)d_in[0];
    const float* bw1 = (const float*)d_in[1];
    const float* sw1 = (const float*)d_in[2];
    const float* sc1 = (const float*)d_in[3];
    const float* bw2 = (const float*)d_in[4];
    const float* sw2 = (const float*)d_in[5];
    const float* sc2 = (const float*)d_in[6];
    const float* bw3 = (const float*)d_in[7];
    const float* sw3 = (const float*)d_in[8];
    const float* sc3 = (const float*)d_in[9];
    const float* w1  = (const float*)d_in[10];
    const float* b1  = (const float*)d_in[11];
    const float* w2  = (const float*)d_in[12];
    const float* b2  = (const float*)d_in[13];

    float* ws  = (float*)d_ws;
    float* W1m = ws;              // 2700
    float* W2m = ws + 2700;       // 2688
    float* W3m = ws + 5388;       // 3024
    float* bf  = ws + 8412;       // 10 (+pad)
    float* Wf  = ws + 8448;       // 34560
    float* o1  = ws + 43008;      // 256*12*12*12 = 442368
    float* o2  = ws + 485376;     // 256*144*4*4  = 589824
    float* x3  = ws + 1075200;    // 256*3456     = 884736
    float* out = (float*)d_out;

    prep_weights<<<3, 256, 0, stream>>>(bw1, sw1, sc1, bw2, sw2, sc2,
                                        bw3, sw3, sc3, W1m, W2m, W3m);
    prep_bf<<<1, 64, 0, stream>>>(b1, w2, b2, bf);
    wf_kernel<<<135, 256, 0, stream>>>(w1, w2, Wf);

    const float h1 = 2.0f / 5.0f, h2 = 2.0f / 10.0f;
    // layer1: K=5, NINT=11, G=8, N=12, C=1, 28x28 -> pooled 12x12
    kan_conv_pool<5, 11, 8, 12, 1, 28, 28, 12, 12>
        <<<576, 256, 0, stream>>>(x, W1m, o1, -3.0f * h1 - 1.0f, 1.0f / h1);
    // layer2: K=4, NINT=16, G=13, N=12, C=12, 12x12 -> pooled 4x4
    kan_conv_pool<4, 16, 13, 12, 12, 12, 12, 4, 4>
        <<<768, 256, 0, stream>>>(o1, W2m, o2, -3.0f * h2 - 1.0f, 1.0f / h2);
    // layer3: K=3, NINT=16, G=13, N=24, C=144, 4x4 -> pooled 1x1
    kan_conv_pool<3, 16, 13, 24, 144, 4, 4, 1, 1>
        <<<576, 256, 0, stream>>>(o2, W3m, x3, -3.0f * h2 - 1.0f, 1.0f / h2);

    fc_kernel<<<640, 256, 0, stream>>>(x3, Wf, bf, out);
}

// Round 2
// 274.666 us; speedup vs baseline: 1.0020x; 1.0020x over previous
//
#include <hip/hip_runtime.h>
#include <math.h>

// ---------------------------------------------------------------------------
// SuperCKAN forward:
//   conv1 (k=5, grid5, n=12)  + pool -> (256,12,12,12)
//   conv2 (k=4, grid10, n=12) + pool -> (256,144,4,4)
//   conv3 (k=3, grid10, n=24) + pool -> (256,3456)
//   fc: x @ (w2@w1)^T + (b1@w2^T + b2) -> (256,10)
// All fp32. Weights merged per layer into [k][n][1+G] tables (scaler folded).
//
// R1 change: all worker grids are EXACT, so the divergent `if (tid>=TOT)
// return;` guards are removed. This puts the wave-uniform weight loads in
// uniform control flow so the compiler can scalarize them (s_load + FMA with
// SGPR operand) instead of per-lane global_load_dword broadcasts.
// ---------------------------------------------------------------------------

#define B_BATCH 256

// ---- prep: merged weight tables -------------------------------------------
__global__ __launch_bounds__(256) void prep_weights(
    const float* __restrict__ bw1, const float* __restrict__ sw1, const float* __restrict__ sc1,
    const float* __restrict__ bw2, const float* __restrict__ sw2, const float* __restrict__ sc2,
    const float* __restrict__ bw3, const float* __restrict__ sw3, const float* __restrict__ sc3,
    float* __restrict__ W1m, float* __restrict__ W2m, float* __restrict__ W3m)
{
    int tid = blockIdx.x * 256 + threadIdx.x;
    if (tid < 300) {                     // layer1: n<12, k<25, G=8
        int n = tid / 25, k = tid % 25;
        float sc = sc1[n * 25 + k];
        W1m[k * 108 + n * 9] = bw1[n * 25 + k];
        for (int g = 0; g < 8; ++g)
            W1m[k * 108 + n * 9 + 1 + g] = sw1[(n * 25 + k) * 8 + g] * sc;
    } else if (tid < 492) {              // layer2: n<12, k<16, G=13
        int i = tid - 300;
        int n = i / 16, k = i % 16;
        float sc = sc2[n * 16 + k];
        W2m[k * 168 + n * 14] = bw2[n * 16 + k];
        for (int g = 0; g < 13; ++g)
            W2m[k * 168 + n * 14 + 1 + g] = sw2[(n * 16 + k) * 13 + g] * sc;
    } else if (tid < 708) {              // layer3: n<24, k<9, G=13
        int i = tid - 492;
        int n = i / 9, k = i % 9;
        float sc = sc3[n * 9 + k];
        W3m[k * 336 + n * 14] = bw3[n * 9 + k];
        for (int g = 0; g < 13; ++g)
            W3m[k * 336 + n * 14 + 1 + g] = sw3[(n * 9 + k) * 13 + g] * sc;
    }
}

// ---- prep: folded bias bf = b1 @ w2^T + b2 --------------------------------
__global__ void prep_bf(const float* __restrict__ b1, const float* __restrict__ w2,
                        const float* __restrict__ b2, float* __restrict__ bf)
{
    int lane = threadIdx.x; // 64 threads
    for (int n = 0; n < 10; ++n) {
        float s = 0.f;
        for (int j = lane; j < 256; j += 64) s = fmaf(b1[j], w2[n * 256 + j], s);
        for (int o = 32; o; o >>= 1) s += __shfl_down(s, o, 64);
        if (lane == 0) bf[n] = s + b2[n];
    }
}

// ---- prep: Wf = w2 @ w1  (10 x 3456) --------------------------------------
// grid 135*256 = 34560 exact: no guard.
__global__ __launch_bounds__(256) void wf_kernel(const float* __restrict__ w1,
                                                 const float* __restrict__ w2,
                                                 float* __restrict__ Wf)
{
    int gid = blockIdx.x * 256 + threadIdx.x;
    int n = gid / 3456, m = gid % 3456;
    float s = 0.f;
    for (int j = 0; j < 256; ++j)
        s = fmaf(w2[n * 256 + j], w1[j * 3456 + m], s);
    Wf[n * 3456 + m] = s;
}

// ---- fused KAN conv + 2x2 maxpool -----------------------------------------
// Thread quad (4 lanes, sub = 2x2 conv position) per pooled output position.
// W layout: [K*K][N][1+G]; g0/invh describe the uniform knot grid.
// Grid is EXACT (B_BATCH*C*POS*4 threads): no divergent early return, so
// uniform-address weight loads scalarize to s_load.
template <int K, int NINT, int G, int N, int C, int HIN, int WIN, int HP, int WP>
__global__ __launch_bounds__(256) void kan_conv_pool(
    const float* __restrict__ in, const float* __restrict__ W,
    float* __restrict__ out, float g0, float invh)
{
    constexpr int NF = 1 + G;
    constexpr int POS = HP * WP;
    int tid = blockIdx.x * 256 + threadIdx.x;

    int sub = tid & 3;
    int rem = tid >> 2;
    int pos = rem % POS;
    int bc  = rem / POS;               // b*C + c
    int pi = pos / WP, pj = pos % WP;
    int p = 2 * pi + (sub >> 1);
    int q = 2 * pj + (sub & 1);

    const float* inp = in + bc * (HIN * WIN);

    float acc[N];
#pragma unroll
    for (int n = 0; n < N; ++n) acc[n] = 0.f;

    for (int dy = 0; dy < K; ++dy) {
#pragma unroll
        for (int dx = 0; dx < K; ++dx) {
            float v = inp[(p + dy) * WIN + (q + dx)];

            // features: f[0]=silu(v); f[1..G]=cubic B-spline bases (4-sparse)
            float s  = (v - g0) * invh;
            float sf = floorf(s);
            int   t  = (int)sf;
            float u  = s - sf;
            float u2 = u * u, u3 = u2 * u;
            float um = 1.0f - u;
            float c0 = um * um * um * (1.0f / 6.0f);
            float c1 = (3.0f * u3 - 6.0f * u2 + 4.0f) * (1.0f / 6.0f);
            float c2 = (-3.0f * u3 + 3.0f * u2 + 3.0f * u + 1.0f) * (1.0f / 6.0f);
            float c3 = u3 * (1.0f / 6.0f);
            bool  inr = (t >= 0) && (t < NINT);
            int   i0  = t - 3;

            float f[NF];
            f[0] = v / (1.0f + __expf(-v));
#pragma unroll
            for (int g = 0; g < G; ++g) {
                int m = g - i0;
                float fg = (m == 0) ? c0 : (m == 1) ? c1 : (m == 2) ? c2
                           : (m == 3) ? c3 : 0.0f;
                f[1 + g] = inr ? fg : 0.0f;
            }

            const float* wk = W + (dy * K + dx) * (N * NF);
#pragma unroll
            for (int n = 0; n < N; ++n)
#pragma unroll
                for (int j = 0; j < NF; ++j)
                    acc[n] = fmaf(f[j], wk[n * NF + j], acc[n]);
        }
    }

    // 2x2 maxpool across the lane quad
#pragma unroll
    for (int n = 0; n < N; ++n) {
        acc[n] = fmaxf(acc[n], __shfl_xor(acc[n], 1, 64));
        acc[n] = fmaxf(acc[n], __shfl_xor(acc[n], 2, 64));
    }

    // each of the 4 lanes writes N/4 channels
    constexpr int NPL = N / 4;
    int n0 = sub * NPL;
    float* op = out + bc * (N * POS) + pos;
#pragma unroll
    for (int i = 0; i < NPL; ++i)
        op[(n0 + i) * POS] = acc[n0 + i];
}

// ---- final GEMV: out = x3 @ Wf^T + bf  (one wave per output) --------------
// grid 640*256/64 = 2560 waves = 256*10 outputs exact: no guard.
__global__ __launch_bounds__(256) void fc_kernel(
    const float* __restrict__ x3, const float* __restrict__ Wf,
    const float* __restrict__ bf, float* __restrict__ out)
{
    int wid  = (blockIdx.x * 256 + threadIdx.x) >> 6;
    int lane = threadIdx.x & 63;
    int b = wid / 10, n = wid - b * 10;
    const float* xr = x3 + b * 3456;
    const float* wr = Wf + n * 3456;
    float s = 0.f;
    for (int t = lane; t < 3456; t += 64)
        s = fmaf(xr[t], wr[t], s);
    for (int o = 32; o; o >>= 1) s += __shfl_down(s, o, 64);
    if (lane == 0) out[wid] = s + bf[n];
}

// ---------------------------------------------------------------------------
extern "C" void kernel_launch(void* const* d_in, const int* in_sizes, int n_in,
                              void* d_out, int out_size, void* d_ws, size_t ws_size,
                              hipStream_t stream)
{
    (void)in_sizes; (void)n_in; (void)out_size; (void)ws_size;
    const float* x   = (const float*)d_in[0];
    const float* bw1 = (const float*)d_in[1];
    const float* sw1 = (const float*)d_in[2];
    const float* sc1 = (const float*)d_in[3];
    const float* bw2 = (const float*)d_in[4];
    const float* sw2 = (const float*)d_in[5];
    const float* sc2 = (const float*)d_in[6];
    const float* bw3 = (const float*)d_in[7];
    const float* sw3 = (const float*)d_in[8];
    const float* sc3 = (const float*)d_in[9];
    const float* w1  = (const float*)d_in[10];
    const float* b1  = (const float*)d_in[11];
    const float* w2  = (const float*)d_in[12];
    const float* b2  = (const float*)d_in[13];

    float* ws  = (float*)d_ws;
    float* W1m = ws;              // 2700
    float* W2m = ws + 2700;       // 2688
    float* W3m = ws + 5388;       // 3024
    float* bf  = ws + 8412;       // 10 (+pad)
    float* Wf  = ws + 8448;       // 34560
    float* o1  = ws + 43008;      // 256*12*12*12 = 442368
    float* o2  = ws + 485376;     // 256*144*4*4  = 589824
    float* x3  = ws + 1075200;    // 256*3456     = 884736
    float* out = (float*)d_out;

    prep_weights<<<3, 256, 0, stream>>>(bw1, sw1, sc1, bw2, sw2, sc2,
                                        bw3, sw3, sc3, W1m, W2m, W3m);
    prep_bf<<<1, 64, 0, stream>>>(b1, w2, b2, bf);
    wf_kernel<<<135, 256, 0, stream>>>(w1, w2, Wf);

    const float h1 = 2.0f / 5.0f, h2 = 2.0f / 10.0f;
    // layer1: K=5, NINT=11, G=8, N=12, C=1, 28x28 -> pooled 12x12
    kan_conv_pool<5, 11, 8, 12, 1, 28, 28, 12, 12>
        <<<576, 256, 0, stream>>>(x, W1m, o1, -3.0f * h1 - 1.0f, 1.0f / h1);
    // layer2: K=4, NINT=16, G=13, N=12, C=12, 12x12 -> pooled 4x4
    kan_conv_pool<4, 16, 13, 12, 12, 12, 12, 4, 4>
        <<<768, 256, 0, stream>>>(o1, W2m, o2, -3.0f * h2 - 1.0f, 1.0f / h2);
    // layer3: K=3, NINT=16, G=13, N=24, C=144, 4x4 -> pooled 1x1
    kan_conv_pool<3, 16, 13, 24, 144, 4, 4, 1, 1>
        <<<576, 256, 0, stream>>>(o2, W3m, x3, -3.0f * h2 - 1.0f, 1.0f / h2);

    fc_kernel<<<640, 256, 0, stream>>>(x3, Wf, bf, out);
}